// Round 2
// baseline (2320.201 us; speedup 1.0000x reference)
//
#include <hip/hip_runtime.h>
#include <math.h>

#define HD 128
#define NBR 8
#define LSTEPS 64
#define TILE_B 32
#define HT_PAD 36     // hT row stride (floats); GEMM reads are wave-uniform broadcasts
#define WS_PAD 132    // wsoft row stride: (4nb+k)%32 distinct across nb -> <=2-way

// workspace layout (floats)
#define WPT_OFF   0        // w_hh permuted-transposed: [k][4*hh+q] = w_hh[q*128+hh][k]   (128*512)
#define WIPT_OFF  65536    // w_ih same layout                                            (128*512)
#define PP_OFF    131072   // P = 0.5 * w_emb@w_ih^T, layout [j][q*128+hh]                (8*512)
#define BIH_OFF   135168   // b_ih permuted [q][hh]                                       (512)
#define BHH_OFF   135680   // b_hh permuted [q][hh]                                       (512)

__global__ __launch_bounds__(256) void setup_kernel(
    const float* __restrict__ w_emb, const float* __restrict__ w_ih,
    const float* __restrict__ w_hh, const float* __restrict__ b_ih,
    const float* __restrict__ b_hh, float* __restrict__ ws)
{
  int tid = blockIdx.x * blockDim.x + threadIdx.x;
  if (tid < 65536) {
    int k = tid >> 9, col = tid & 511;
    int hh = col >> 2, q = col & 3;
    ws[WPT_OFF + tid]  = w_hh[(q*HD + hh)*HD + k];
    ws[WIPT_OFF + tid] = w_ih[(q*HD + hh)*HD + k];
  }
  if (tid < 4096) {
    int j = tid >> 9, rem = tid & 511;
    int q = rem >> 7, hh2 = rem & 127;
    const float* wr = w_ih + (q*HD + hh2)*HD;
    const float* er = w_emb + j*HD;
    float s = 0.f;
    for (int k = 0; k < HD; ++k) s = fmaf(er[k], wr[k], s);
    ws[PP_OFF + (size_t)j*512 + q*HD + hh2] = 0.5f * s;   // pre-halved
  }
  if (tid < 512) {
    int q = tid >> 7, hh2 = tid & 127;
    ws[BIH_OFF + tid] = b_ih[q*HD + hh2];
    ws[BHH_OFF + tid] = b_hh[q*HD + hh2];
  }
}

__global__ __launch_bounds__(512, 4) void ctrl_kernel(
    const int* __restrict__ class_ids,
    const float* __restrict__ gumbel_u,
    const float* __restrict__ g_emb,
    const float* __restrict__ w_soft,
    const float* __restrict__ ws,
    float* __restrict__ out,
    int Btot)
{
  __shared__ float hT[HD * HT_PAD];      // 18432 B, h transposed [k][b]
  __shared__ float wsoft_l[NBR * WS_PAD];// 4224 B
  __shared__ float pp_l[NBR * 512];      // 16384 B, 0.5*P, [br][q*128+hh]
  __shared__ int   br_l[TILE_B];         // 128 B     total ~39.2 KB -> 2 blocks/CU

  const int tid = threadIdx.x;
  const int b0  = blockIdx.x * TILE_B;
  const size_t BL = (size_t)Btot * LSTEPS;

  const float* __restrict__ wpT  = ws + WPT_OFF;
  const float* __restrict__ wipT = ws + WIPT_OFF;

  // stage w_soft (padded) and P into LDS
  for (int i = tid; i < NBR*HD; i += 512) {
    int nb = i >> 7, k = i & 127;
    wsoft_l[nb*WS_PAD + k] = w_soft[i];
  }
  for (int i = tid; i < NBR*512; i += 512) pp_l[i] = ws[PP_OFF + i];

  const int hh = tid & 127;   // gate row within quadrant
  const int bg = tid >> 7;    // batch group 0..3 (8 batches each)

  float bsum[4];
  #pragma unroll
  for (int q = 0; q < 4; ++q)
    bsum[q] = ws[BIH_OFF + q*HD + hh] + ws[BHH_OFF + q*HD + hh];

  // ---- stage x0^T = g_emb[class_ids]^T into hT ----
  {
    int sb = tid >> 4;        // 0..31 batch
    int kc = tid & 15;        // k-chunk of 8
    int cid = class_ids[b0 + sb];
    const float* src = g_emb + (size_t)cid * HD + kc*8;
    float4 v0 = *(const float4*)(src);
    float4 v1 = *(const float4*)(src + 4);
    int kb = kc*8;
    hT[(kb+0)*HT_PAD + sb] = v0.x;  hT[(kb+1)*HT_PAD + sb] = v0.y;
    hT[(kb+2)*HT_PAD + sb] = v0.z;  hT[(kb+3)*HT_PAD + sb] = v0.w;
    hT[(kb+4)*HT_PAD + sb] = v1.x;  hT[(kb+5)*HT_PAD + sb] = v1.y;
    hT[(kb+6)*HT_PAD + sb] = v1.z;  hT[(kb+7)*HT_PAD + sb] = v1.w;
  }
  __syncthreads();

  // ---- q0 = x0 @ w_ih^T (permuted), kept in registers ----
  float q0[4][8];
  #pragma unroll
  for (int q = 0; q < 4; ++q)
    #pragma unroll
    for (int j = 0; j < 8; ++j) q0[q][j] = 0.f;

  #pragma unroll 4
  for (int k = 0; k < HD; ++k) {
    float4 w = *(const float4*)(wipT + k*512 + 4*hh);
    const float* hr = &hT[k*HT_PAD + bg*8];
    float4 ha = *(const float4*)(hr);
    float4 hb = *(const float4*)(hr+4);
    #pragma unroll
    for (int q = 0; q < 4; ++q) {
      float wq = (q==0)?w.x:((q==1)?w.y:((q==2)?w.z:w.w));
      q0[q][0] = fmaf(ha.x, wq, q0[q][0]);
      q0[q][1] = fmaf(ha.y, wq, q0[q][1]);
      q0[q][2] = fmaf(ha.z, wq, q0[q][2]);
      q0[q][3] = fmaf(ha.w, wq, q0[q][3]);
      q0[q][4] = fmaf(hb.x, wq, q0[q][4]);
      q0[q][5] = fmaf(hb.y, wq, q0[q][5]);
      q0[q][6] = fmaf(hb.z, wq, q0[q][6]);
      q0[q][7] = fmaf(hb.w, wq, q0[q][7]);
    }
  }
  __syncthreads();

  float c[8];
  #pragma unroll
  for (int j = 0; j < 8; ++j) c[j] = 0.f;

  // sampling-phase lane roles
  const int s_nb = tid & 7;
  const int s_kh = (tid >> 3) & 1;
  const int s_lb = tid >> 4;            // 0..31
  const int laneBase = (tid & 63) & ~7; // group base within wave

  for (int t = 0; t < LSTEPS; ++t) {
    // prefetch this step's gumbel u (coalesced; overlaps GEMM)
    float uv = gumbel_u[((size_t)t * Btot + (b0 + s_lb)) * NBR + s_nb];

    // ---- GEMM: acc = h @ w_hh^T (skipped at t=0: h0 = 0) ----
    float acc[4][8];
    #pragma unroll
    for (int q = 0; q < 4; ++q)
      #pragma unroll
      for (int j = 0; j < 8; ++j) acc[q][j] = 0.f;

    if (t > 0) {
      #pragma unroll 4
      for (int k = 0; k < HD; ++k) {
        float4 w = *(const float4*)(wpT + k*512 + 4*hh);
        const float* hr = &hT[k*HT_PAD + bg*8];
        float4 ha = *(const float4*)(hr);
        float4 hb = *(const float4*)(hr+4);
        #pragma unroll
        for (int q = 0; q < 4; ++q) {
          float wq = (q==0)?w.x:((q==1)?w.y:((q==2)?w.z:w.w));
          acc[q][0] = fmaf(ha.x, wq, acc[q][0]);
          acc[q][1] = fmaf(ha.y, wq, acc[q][1]);
          acc[q][2] = fmaf(ha.z, wq, acc[q][2]);
          acc[q][3] = fmaf(ha.w, wq, acc[q][3]);
          acc[q][4] = fmaf(hb.x, wq, acc[q][4]);
          acc[q][5] = fmaf(hb.y, wq, acc[q][5]);
          acc[q][6] = fmaf(hb.z, wq, acc[q][6]);
          acc[q][7] = fmaf(hb.w, wq, acc[q][7]);
        }
      }
    }

    // ---- combine x-part + bias, LSTM pointwise (registers only) ----
    float h2v[8];
    #pragma unroll
    for (int j = 0; j < 8; ++j) {
      float xw[4];
      if (t == 0) {
        #pragma unroll
        for (int q = 0; q < 4; ++q) xw[q] = q0[q][j];
      } else {
        int br = br_l[bg*8 + j];
        const float* pr = &pp_l[br*512 + hh];   // bank = hh%32 -> conflict-free
        #pragma unroll
        for (int q = 0; q < 4; ++q) xw[q] = pr[q*HD] + q0[q][j];  // both pre-halved
      }
      float gi = (xw[0] + acc[0][j]) + bsum[0];
      float gf = (xw[1] + acc[1][j]) + bsum[1];
      float gg = (xw[2] + acc[2][j]) + bsum[2];
      float go = (xw[3] + acc[3][j]) + bsum[3];
      float iv = 1.f/(1.f + expf(-gi));
      float fv = 1.f/(1.f + expf(-gf));
      float gv = tanhf(gg);
      float ov = 1.f/(1.f + expf(-go));
      float c2 = fv*c[j] + iv*gv;
      c[j] = c2;
      h2v[j] = ov * tanhf(c2);
    }
    if (t == 0) {  // q0 is used scaled by 0.5 for all t>0
      #pragma unroll
      for (int q = 0; q < 4; ++q)
        #pragma unroll
        for (int j = 0; j < 8; ++j) q0[q][j] *= 0.5f;
    }
    __syncthreads();   // (A) all hT reads done before overwrite

    {
      float* dst = &hT[hh*HT_PAD + bg*8];
      *(float4*)(dst)   = make_float4(h2v[0],h2v[1],h2v[2],h2v[3]);
      *(float4*)(dst+4) = make_float4(h2v[4],h2v[5],h2v[6],h2v[7]);
    }
    __syncthreads();   // (B) new h visible

    // ---- logits + sampling, all 512 threads: (lb, nb, k-half) ----
    {
      float s = 0.f;
      const int kb = s_kh * 64;
      #pragma unroll 8
      for (int i = 0; i < 64; ++i) {
        int k = kb + i;
        s = fmaf(hT[k*HT_PAD + s_lb], wsoft_l[s_nb*WS_PAD + k], s);
      }
      s += __shfl_xor(s, 8);             // combine k-halves (both kh now hold full dot)
      float lg = 2.5f * tanhf(s * 0.2f);

      float uc  = fminf(fmaxf(uv, 1e-8f), 0.99999999f);
      float y   = lg - logf(-logf(uc));
      int   idx = s_nb;
      #pragma unroll
      for (int mask = 1; mask <= 4; mask <<= 1) {
        float oy  = __shfl_xor(y, mask);
        int   oi  = __shfl_xor(idx, mask);
        if (oy > y || (oy == y && oi < idx)) { y = oy; idx = oi; }
      }
      float m = lg;
      #pragma unroll
      for (int mask = 1; mask <= 4; mask <<= 1)
        m = fmaxf(m, __shfl_xor(m, mask));
      float e = expf(lg - m);
      float se = e;
      #pragma unroll
      for (int mask = 1; mask <= 4; mask <<= 1)
        se += __shfl_xor(se, mask);
      float lse = logf(se);
      float lpi = (lg - m) - lse;
      float pi  = e / se;
      float epi = pi * lpi;
      float ent = epi;
      #pragma unroll
      for (int mask = 1; mask <= 4; mask <<= 1)
        ent += __shfl_xor(ent, mask);
      ent = -ent;
      int srcLane = laneBase | idx;
      float lp_sel = __shfl(lpi, srcLane);
      float pr_sel = __shfl(pi,  srcLane);

      if ((tid & 15) == 0) {             // nb==0 && kh==0: one writer per lb
        size_t row = (size_t)(b0 + s_lb) * LSTEPS + t;
        out[row]        = (float)idx;
        out[BL + row]   = lp_sel;
        out[2*BL + row] = ent;
        out[3*BL + row] = pr_sel;
        br_l[s_lb] = idx;
      }
    }
    __syncthreads();   // (E) br_l visible for next step's combine
  }
}

extern "C" void kernel_launch(void* const* d_in, const int* in_sizes, int n_in,
                              void* d_out, int out_size, void* d_ws, size_t ws_size,
                              hipStream_t stream) {
  const int*   class_ids = (const int*)d_in[0];
  const float* gumbel_u  = (const float*)d_in[1];
  const float* g_emb     = (const float*)d_in[2];
  const float* w_emb     = (const float*)d_in[3];
  const float* w_soft    = (const float*)d_in[4];
  const float* w_ih      = (const float*)d_in[5];
  const float* w_hh      = (const float*)d_in[6];
  const float* b_ih      = (const float*)d_in[7];
  const float* b_hh      = (const float*)d_in[8];
  float* out = (float*)d_out;
  float* ws  = (float*)d_ws;
  int B = in_sizes[0];

  hipLaunchKernelGGL(setup_kernel, dim3(256), dim3(256), 0, stream,
                     w_emb, w_ih, w_hh, b_ih, b_hh, ws);
  hipLaunchKernelGGL(ctrl_kernel, dim3(B / TILE_B), dim3(512), 0, stream,
                     class_ids, gumbel_u, g_emb, w_soft, ws, out, B);
}

// Round 3
// 2225.453 us; speedup vs baseline: 1.0426x; 1.0426x over previous
//
#include <hip/hip_runtime.h>
#include <math.h>

#define HD 128
#define NBR 8
#define LSTEPS 64
#define TILE_B 32
#define HT_PAD 36      // hT row stride (floats)
#define PART_PAD 65    // part_l row stride

// workspace layout (floats)
#define WHH2_OFF  0        // w_hh relaid: [(hh*128+k)*4+q] = w_hh[(q*128+hh)*128+k]  (65536)
#define WIH2_OFF  65536    // w_ih same layout                                         (65536)
#define PP_OFF    131072   // 0.5 * w_emb@w_ih^T: [(br*128+hh)*4+q]                    (4096)
#define BS_OFF    135168   // b_ih+b_hh, [q*128+hh]                                    (512)

__device__ __forceinline__ float fsig(float x) {
  return __builtin_amdgcn_rcpf(1.f + __expf(-x));
}
__device__ __forceinline__ float ftanh(float x) {
  return 1.f - 2.f * __builtin_amdgcn_rcpf(1.f + __expf(2.f * x));
}

__global__ __launch_bounds__(256) void setup_kernel(
    const float* __restrict__ w_emb, const float* __restrict__ w_ih,
    const float* __restrict__ w_hh, const float* __restrict__ b_ih,
    const float* __restrict__ b_hh, float* __restrict__ ws)
{
  int tid = blockIdx.x * blockDim.x + threadIdx.x;
  if (tid < 65536) {
    int hh = tid >> 9, k = (tid >> 2) & 127, q = tid & 3;
    ws[WHH2_OFF + tid] = w_hh[(q*HD + hh)*HD + k];
    ws[WIH2_OFF + tid] = w_ih[(q*HD + hh)*HD + k];
  }
  if (tid < 4096) {
    int j = tid >> 9, rem = tid & 511;
    int hh2 = rem >> 2, q = rem & 3;
    const float* wr = w_ih + (q*HD + hh2)*HD;
    const float* er = w_emb + j*HD;
    float s = 0.f;
    for (int k = 0; k < HD; ++k) s = fmaf(er[k], wr[k], s);
    ws[PP_OFF + tid] = 0.5f * s;
  }
  if (tid < 512) ws[BS_OFF + tid] = b_ih[tid] + b_hh[tid];
}

__global__ __launch_bounds__(256, 2) void ctrl_kernel(
    const int* __restrict__ class_ids,
    const float* __restrict__ gumbel_u,
    const float* __restrict__ g_emb,
    const float* __restrict__ w_soft,
    const float* __restrict__ ws,
    float* __restrict__ out,
    int Btot)
{
  __shared__ float hT[HD * HT_PAD];          // 18432 B  h^T [k][b]
  __shared__ float ws_l[NBR * HD];           // 4096 B   w_soft
  __shared__ float pp_l[NBR * HD * 4];       // 16384 B  0.5*P as float4 rows [(br*128+hh)*4+q]
  __shared__ float part_l[TILE_B * PART_PAD];// 8320 B
  __shared__ int   br_l[TILE_B];             // 128 B    total ~47.3 KB -> 2 blocks/CU

  const int tid = threadIdx.x;
  const int b0  = blockIdx.x * TILE_B;
  const size_t BL = (size_t)Btot * LSTEPS;

  for (int i = tid; i < NBR*HD; i += 256) ws_l[i] = w_soft[i];
  for (int i = tid; i < NBR*HD*4; i += 256) pp_l[i] = ws[PP_OFF + i];

  const int hh = tid & 127;    // gate row (within each quadrant)
  const int bg = tid >> 7;     // batch half: batches bg*16 .. bg*16+15

  float bsq[4];
  #pragma unroll
  for (int q = 0; q < 4; ++q) bsq[q] = ws[BS_OFF + q*HD + hh];

  // per-thread contiguous weight streams
  const float* __restrict__ whhp = ws + WHH2_OFF + hh*512;
  const float* __restrict__ wihp = ws + WIH2_OFF + hh*512;
  const float* hTb = hT + bg*16;

  // ---- stage x0^T into hT ----
  {
    int sb = tid >> 3;         // 0..31
    int kc = tid & 7;          // chunk of 16 k
    int cid = class_ids[b0 + sb];
    const float* src = g_emb + (size_t)cid * HD + kc*16;
    #pragma unroll
    for (int ii = 0; ii < 4; ++ii) {
      float4 v = *(const float4*)(src + 4*ii);
      int kb = kc*16 + 4*ii;
      hT[(kb+0)*HT_PAD + sb] = v.x;
      hT[(kb+1)*HT_PAD + sb] = v.y;
      hT[(kb+2)*HT_PAD + sb] = v.z;
      hT[(kb+3)*HT_PAD + sb] = v.w;
    }
  }
  __syncthreads();

  // ---- q0 = x0 @ w_ih^T ----
  float q0[4][16];
  #pragma unroll
  for (int q = 0; q < 4; ++q)
    #pragma unroll
    for (int j = 0; j < 16; ++j) q0[q][j] = 0.f;

  #pragma unroll 8
  for (int k = 0; k < HD; ++k) {
    float4 w = *(const float4*)(wihp + k*4);
    const float* hr = hTb + k*HT_PAD;
    float4 h0 = *(const float4*)(hr);
    float4 h1 = *(const float4*)(hr+4);
    float4 h2 = *(const float4*)(hr+8);
    float4 h3 = *(const float4*)(hr+12);
    #pragma unroll
    for (int q = 0; q < 4; ++q) {
      float wq = (q==0)?w.x:((q==1)?w.y:((q==2)?w.z:w.w));
      q0[q][0]=fmaf(h0.x,wq,q0[q][0]); q0[q][1]=fmaf(h0.y,wq,q0[q][1]);
      q0[q][2]=fmaf(h0.z,wq,q0[q][2]); q0[q][3]=fmaf(h0.w,wq,q0[q][3]);
      q0[q][4]=fmaf(h1.x,wq,q0[q][4]); q0[q][5]=fmaf(h1.y,wq,q0[q][5]);
      q0[q][6]=fmaf(h1.z,wq,q0[q][6]); q0[q][7]=fmaf(h1.w,wq,q0[q][7]);
      q0[q][8]=fmaf(h2.x,wq,q0[q][8]); q0[q][9]=fmaf(h2.y,wq,q0[q][9]);
      q0[q][10]=fmaf(h2.z,wq,q0[q][10]); q0[q][11]=fmaf(h2.w,wq,q0[q][11]);
      q0[q][12]=fmaf(h3.x,wq,q0[q][12]); q0[q][13]=fmaf(h3.y,wq,q0[q][13]);
      q0[q][14]=fmaf(h3.z,wq,q0[q][14]); q0[q][15]=fmaf(h3.w,wq,q0[q][15]);
    }
  }
  __syncthreads();

  float c[16];
  #pragma unroll
  for (int j = 0; j < 16; ++j) c[j] = 0.f;

  for (int t = 0; t < LSTEPS; ++t) {
    // prefetch gumbel u (32 lanes; overlaps GEMM)
    float4 ua = make_float4(0,0,0,0), ub = make_float4(0,0,0,0);
    if (tid < TILE_B) {
      const float* up = gumbel_u + ((size_t)t * Btot + (b0 + tid)) * NBR;
      ua = *(const float4*)up;
      ub = *(const float4*)(up + 4);
    }

    float h2v[16];

    if (t == 0) {
      #pragma unroll
      for (int j = 0; j < 16; ++j) {
        float gi = q0[0][j] + bsq[0];
        float gf = q0[1][j] + bsq[1];
        float gg = q0[2][j] + bsq[2];
        float go = q0[3][j] + bsq[3];
        float c2 = fsig(gf)*c[j] + fsig(gi)*ftanh(gg);
        c[j] = c2;
        h2v[j] = fsig(go) * ftanh(c2);
      }
      // fold: q0 <- 0.5*q0 + bsum  (the form used for every t>0)
      #pragma unroll
      for (int q = 0; q < 4; ++q)
        #pragma unroll
        for (int j = 0; j < 16; ++j) q0[q][j] = fmaf(q0[q][j], 0.5f, bsq[q]);
    } else {
      // ---- GEMM: acc = h @ w_hh^T ----
      float acc[4][16];
      #pragma unroll
      for (int q = 0; q < 4; ++q)
        #pragma unroll
        for (int j = 0; j < 16; ++j) acc[q][j] = 0.f;

      #pragma unroll 8
      for (int k = 0; k < HD; ++k) {
        float4 w = *(const float4*)(whhp + k*4);
        const float* hr = hTb + k*HT_PAD;
        float4 h0 = *(const float4*)(hr);
        float4 h1 = *(const float4*)(hr+4);
        float4 h2 = *(const float4*)(hr+8);
        float4 h3 = *(const float4*)(hr+12);
        #pragma unroll
        for (int q = 0; q < 4; ++q) {
          float wq = (q==0)?w.x:((q==1)?w.y:((q==2)?w.z:w.w));
          acc[q][0]=fmaf(h0.x,wq,acc[q][0]); acc[q][1]=fmaf(h0.y,wq,acc[q][1]);
          acc[q][2]=fmaf(h0.z,wq,acc[q][2]); acc[q][3]=fmaf(h0.w,wq,acc[q][3]);
          acc[q][4]=fmaf(h1.x,wq,acc[q][4]); acc[q][5]=fmaf(h1.y,wq,acc[q][5]);
          acc[q][6]=fmaf(h1.z,wq,acc[q][6]); acc[q][7]=fmaf(h1.w,wq,acc[q][7]);
          acc[q][8]=fmaf(h2.x,wq,acc[q][8]); acc[q][9]=fmaf(h2.y,wq,acc[q][9]);
          acc[q][10]=fmaf(h2.z,wq,acc[q][10]); acc[q][11]=fmaf(h2.w,wq,acc[q][11]);
          acc[q][12]=fmaf(h3.x,wq,acc[q][12]); acc[q][13]=fmaf(h3.y,wq,acc[q][13]);
          acc[q][14]=fmaf(h3.z,wq,acc[q][14]); acc[q][15]=fmaf(h3.w,wq,acc[q][15]);
        }
      }

      // ---- combine + LSTM pointwise ----
      #pragma unroll
      for (int j = 0; j < 16; ++j) {
        int br = br_l[bg*16 + j];
        float4 pv = *(const float4*)(&pp_l[(br*HD + hh)*4]);
        float gi = (acc[0][j] + q0[0][j]) + pv.x;
        float gf = (acc[1][j] + q0[1][j]) + pv.y;
        float gg = (acc[2][j] + q0[2][j]) + pv.z;
        float go = (acc[3][j] + q0[3][j]) + pv.w;
        float c2 = fsig(gf)*c[j] + fsig(gi)*ftanh(gg);
        c[j] = c2;
        h2v[j] = fsig(go) * ftanh(c2);
      }
    }
    __syncthreads();   // (A) all hT reads done before overwrite

    {
      float* dst = &hT[hh*HT_PAD + bg*16];
      *(float4*)(dst)    = make_float4(h2v[0],h2v[1],h2v[2],h2v[3]);
      *(float4*)(dst+4)  = make_float4(h2v[4],h2v[5],h2v[6],h2v[7]);
      *(float4*)(dst+8)  = make_float4(h2v[8],h2v[9],h2v[10],h2v[11]);
      *(float4*)(dst+12) = make_float4(h2v[12],h2v[13],h2v[14],h2v[15]);
    }
    __syncthreads();   // (B) new h visible

    // ---- logit partials: (lb = tid&31, ch = tid>>5), 16-k chunk each ----
    {
      int lb = tid & 31, ch = tid >> 5;
      float part[8];
      #pragma unroll
      for (int nb = 0; nb < 8; ++nb) part[nb] = 0.f;
      #pragma unroll
      for (int i = 0; i < 16; ++i) {
        float hvv = hT[(ch*16 + i)*HT_PAD + lb];
        #pragma unroll
        for (int nb = 0; nb < 8; ++nb)
          part[nb] = fmaf(hvv, ws_l[nb*HD + ch*16 + i], part[nb]);
      }
      #pragma unroll
      for (int nb = 0; nb < 8; ++nb)
        part_l[lb*PART_PAD + nb*8 + ch] = part[nb];
    }
    __syncthreads();   // (C)

    // ---- sampling: one thread per batch row ----
    if (tid < TILE_B) {
      int lb = tid;
      float lg[8];
      #pragma unroll
      for (int nb = 0; nb < 8; ++nb) {
        float s = 0.f;
        #pragma unroll
        for (int ch = 0; ch < 8; ++ch) s += part_l[lb*PART_PAD + nb*8 + ch];
        lg[nb] = 2.5f * ftanh(s * 0.2f);
      }
      float uv[8] = {ua.x,ua.y,ua.z,ua.w,ub.x,ub.y,ub.z,ub.w};
      int br = 0; float best;
      {
        float uc = fminf(fmaxf(uv[0], 1e-8f), 0.99999999f);
        best = lg[0] - __logf(-__logf(uc));
      }
      #pragma unroll
      for (int nb = 1; nb < 8; ++nb) {
        float uc = fminf(fmaxf(uv[nb], 1e-8f), 0.99999999f);
        float y = lg[nb] - __logf(-__logf(uc));
        if (y > best) { best = y; br = nb; }
      }
      float m = lg[0];
      #pragma unroll
      for (int nb = 1; nb < 8; ++nb) m = fmaxf(m, lg[nb]);
      float se = 0.f;
      #pragma unroll
      for (int nb = 0; nb < 8; ++nb) se += __expf(lg[nb] - m);
      float lse = __logf(se);
      float lp = (lg[br] - m) - lse;
      float ent = 0.f;
      #pragma unroll
      for (int nb = 0; nb < 8; ++nb) {
        float lpi = (lg[nb] - m) - lse;
        ent -= __expf(lpi) * lpi;
      }
      size_t row = (size_t)(b0 + lb) * LSTEPS + t;
      out[row]        = (float)br;
      out[BL + row]   = lp;
      out[2*BL + row] = ent;
      out[3*BL + row] = __expf(lp);
      br_l[lb] = br;
    }
    __syncthreads();   // (E) br_l visible for next step
  }
}

extern "C" void kernel_launch(void* const* d_in, const int* in_sizes, int n_in,
                              void* d_out, int out_size, void* d_ws, size_t ws_size,
                              hipStream_t stream) {
  const int*   class_ids = (const int*)d_in[0];
  const float* gumbel_u  = (const float*)d_in[1];
  const float* g_emb     = (const float*)d_in[2];
  const float* w_emb     = (const float*)d_in[3];
  const float* w_soft    = (const float*)d_in[4];
  const float* w_ih      = (const float*)d_in[5];
  const float* w_hh      = (const float*)d_in[6];
  const float* b_ih      = (const float*)d_in[7];
  const float* b_hh      = (const float*)d_in[8];
  float* out = (float*)d_out;
  float* ws  = (float*)d_ws;
  int B = in_sizes[0];

  hipLaunchKernelGGL(setup_kernel, dim3(256), dim3(256), 0, stream,
                     w_emb, w_ih, w_hh, b_ih, b_hh, ws);
  hipLaunchKernelGGL(ctrl_kernel, dim3(B / TILE_B), dim3(256), 0, stream,
                     class_ids, gumbel_u, g_emb, w_soft, ws, out, B);
}